// Round 1
// baseline (199.730 us; speedup 1.0000x reference)
//
#include <hip/hip_runtime.h>
#include <math.h>

// TopologyHead: persistence image (B,64,64) + persistence landscapes (B,5,256)
// B=64, N=4096. Output = [image flat 262144][landscapes flat 81920], fp32.
//
// Structure:
//  k_minmax       : per-batch min birth / max death -> ws[0..63], ws[64..127]
//  k_img_partial  : K-split rank-1 accumulation, 64-thread blocks, 8x8 reg tile
//  k_img_norm     : sum KC partials, per-batch max, normalize, write image
//  k_land_partial : per-(b, point-chunk) top-5 tents per r (branchless insert)
//  k_land_merge   : merge PC partial top-5 lists -> landscapes

#define B_   64
#define N_   4096
#define HW_  64
#define RES_ 256
#define EPSF 1e-8f

// ---------------- kernel 1: per-batch min birth / max death ----------------
__global__ __launch_bounds__(256) void k_minmax(const float* __restrict__ pairs,
                                                float* __restrict__ wsf) {
    int b = blockIdx.x, tid = threadIdx.x;
    const float2* pr = (const float2*)pairs + (size_t)b * N_;
    float mn = 1e30f, mx = -1e30f;
    #pragma unroll
    for (int i = 0; i < N_ / 256; ++i) {
        float2 v = pr[tid + i * 256];
        mn = fminf(mn, v.x);
        mx = fmaxf(mx, v.y);
    }
    #pragma unroll
    for (int off = 32; off > 0; off >>= 1) {
        mn = fminf(mn, __shfl_xor(mn, off, 64));
        mx = fmaxf(mx, __shfl_xor(mx, off, 64));
    }
    __shared__ float smn[4], smx[4];
    if ((tid & 63) == 0) { smn[tid >> 6] = mn; smx[tid >> 6] = mx; }
    __syncthreads();
    if (tid == 0) {
        mn = fminf(fminf(smn[0], smn[1]), fminf(smn[2], smn[3]));
        mx = fmaxf(fmaxf(smx[0], smx[1]), fmaxf(smx[2], smx[3]));
        wsf[b]      = mn;
        wsf[64 + b] = mx;
    }
}

// ------------- kernel 2: image partial (K-split rank-1 updates) -------------
// 64 threads = 1 wave. Lane (ty,tx) owns 8x8 tile: h in [ty*8, ty*8+8),
// w in [tx*8, tx*8+8). LDS rows padded to 68 floats: 16B-aligned rows,
// stage writes lane=coordinate -> 2-way bank alias (free), fragment reads
// are ds_read_b128 broadcast over 8 distinct addresses (2-way, free).
__global__ __launch_bounds__(64) void k_img_partial(const float* __restrict__ pairs,
                                                    const float* __restrict__ sigp,
                                                    float* __restrict__ part, int KC) {
    int kc = blockIdx.x, b = blockIdx.y;
    int chunk = N_ / KC;
    int n0 = kc * chunk;
    float sigma = sigp[0];
    float c = 0.5f / (sigma * sigma);       // 1/(2 sigma^2)
    int t = threadIdx.x;                    // 0..63 = coordinate index this lane stages
    float xi = (float)t * (1.0f / 63.0f);   // grid value (grid_x == grid_y)

    __shared__ float gxl[32][68];
    __shared__ float gyl[32][68];

    float acc[8][8];
    #pragma unroll
    for (int i = 0; i < 8; ++i)
        #pragma unroll
        for (int j = 0; j < 8; ++j) acc[i][j] = 0.0f;

    int ty = t >> 3, tx = t & 7;
    int h0 = ty * 8, w0 = tx * 8;

    const float* pb = pairs + 2 * ((size_t)b * N_ + n0);

    for (int s = 0; s < chunk; s += 32) {
        __syncthreads();
        #pragma unroll 8
        for (int q = 0; q < 32; ++q) {
            float bp = pb[2 * (s + q)];         // uniform -> s_load
            float dp = pb[2 * (s + q) + 1];
            float pe = dp - bp;                  // persistence (== weight)
            float dx = xi - bp;                  // birth_n/(1+1e-8) == birth in fp32
            float dy = xi - pe;
            gxl[q][t] = __expf(-dx * dx * c);
            gyl[q][t] = pe * __expf(-dy * dy * c);
        }
        __syncthreads();
        #pragma unroll 4
        for (int q = 0; q < 32; ++q) {
            float4 ya = *(const float4*)&gyl[q][h0];
            float4 yb = *(const float4*)&gyl[q][h0 + 4];
            float4 xa = *(const float4*)&gxl[q][w0];
            float4 xb = *(const float4*)&gxl[q][w0 + 4];
            float gy[8] = {ya.x, ya.y, ya.z, ya.w, yb.x, yb.y, yb.z, yb.w};
            float gx[8] = {xa.x, xa.y, xa.z, xa.w, xb.x, xb.y, xb.z, xb.w};
            #pragma unroll
            for (int i = 0; i < 8; ++i)
                #pragma unroll
                for (int j = 0; j < 8; ++j)
                    acc[i][j] = fmaf(gy[i], gx[j], acc[i][j]);
        }
    }

    float* dst = part + (size_t)(b * KC + kc) * (HW_ * HW_);
    #pragma unroll
    for (int i = 0; i < 8; ++i) {
        *(float4*)&dst[(h0 + i) * HW_ + w0] =
            make_float4(acc[i][0], acc[i][1], acc[i][2], acc[i][3]);
        *(float4*)&dst[(h0 + i) * HW_ + w0 + 4] =
            make_float4(acc[i][4], acc[i][5], acc[i][6], acc[i][7]);
    }
}

// ------------- kernel 3: reduce partials, find max, normalize -------------
__global__ __launch_bounds__(256) void k_img_norm(const float* __restrict__ part,
                                                  float* __restrict__ out, int KC) {
    int b = blockIdx.x, tid = threadIdx.x;
    const float* src = part + (size_t)b * KC * (HW_ * HW_);
    float s[16];
    #pragma unroll
    for (int i = 0; i < 16; ++i) {
        int pix = i * 256 + tid;
        float v = 0.0f;
        for (int kc = 0; kc < KC; ++kc) v += src[(size_t)kc * (HW_ * HW_) + pix];
        s[i] = v;
    }
    float m = s[0];
    #pragma unroll
    for (int i = 1; i < 16; ++i) m = fmaxf(m, s[i]);
    #pragma unroll
    for (int off = 32; off > 0; off >>= 1) m = fmaxf(m, __shfl_xor(m, off, 64));
    __shared__ float sm[4];
    if ((tid & 63) == 0) sm[tid >> 6] = m;
    __syncthreads();
    m = fmaxf(fmaxf(sm[0], sm[1]), fmaxf(sm[2], sm[3]));
    float inv = 1.0f / (m + EPSF);
    #pragma unroll
    for (int i = 0; i < 16; ++i)
        out[(size_t)b * (HW_ * HW_) + i * 256 + tid] = s[i] * inv;
}

// ------------- kernel 4: landscape partial top-5 per (b, chunk, r) -------------
__global__ __launch_bounds__(256) void k_land_partial(const float* __restrict__ pairs,
                                                      const float* __restrict__ wsf,
                                                      float* __restrict__ lp, int PC) {
    extern __shared__ float4 pts[];               // chunk/2 float4 = chunk points
    int pc = blockIdx.x, b = blockIdx.y, tid = threadIdx.x;
    int chunk = N_ / PC;
    int n0 = pc * chunk;
    int np4 = chunk >> 1;
    const float4* src = (const float4*)(pairs + 2 * ((size_t)b * N_ + n0));
    for (int i = tid; i < np4; i += 256) pts[i] = src[i];
    __syncthreads();

    float minb = wsf[b], maxd = wsf[64 + b];
    float t_r = minb + (maxd - minb) * ((float)tid * (1.0f / 255.0f));

    float v0 = 0.f, v1 = 0.f, v2 = 0.f, v3 = 0.f, v4 = 0.f;  // tents >= 0
    #pragma unroll 4
    for (int p = 0; p < np4; ++p) {
        float4 q = pts[p];                        // broadcast read, 2 points
        {
            float x = fmaxf(fminf(t_r - q.x, q.y - t_r), 0.0f);
            float a;
            a = fmaxf(v0, x); x = fminf(v0, x); v0 = a;
            a = fmaxf(v1, x); x = fminf(v1, x); v1 = a;
            a = fmaxf(v2, x); x = fminf(v2, x); v2 = a;
            a = fmaxf(v3, x); x = fminf(v3, x); v3 = a;
            v4 = fmaxf(v4, x);
        }
        {
            float x = fmaxf(fminf(t_r - q.z, q.w - t_r), 0.0f);
            float a;
            a = fmaxf(v0, x); x = fminf(v0, x); v0 = a;
            a = fmaxf(v1, x); x = fminf(v1, x); v1 = a;
            a = fmaxf(v2, x); x = fminf(v2, x); v2 = a;
            a = fmaxf(v3, x); x = fminf(v3, x); v3 = a;
            v4 = fmaxf(v4, x);
        }
    }
    float* d = lp + ((size_t)(b * PC + pc) * RES_ + tid) * 5;
    d[0] = v0; d[1] = v1; d[2] = v2; d[3] = v3; d[4] = v4;
}

// ------------- kernel 5: merge PC partial top-5 lists, write landscapes -------------
__global__ __launch_bounds__(256) void k_land_merge(const float* __restrict__ lp,
                                                    float* __restrict__ out, int PC) {
    int b = blockIdx.x, r = threadIdx.x;
    const float* s0 = lp + ((size_t)b * PC * RES_ + r) * 5;
    float v0 = s0[0], v1 = s0[1], v2 = s0[2], v3 = s0[3], v4 = s0[4];
    for (int pc = 1; pc < PC; ++pc) {
        const float* sp = lp + ((size_t)(b * PC + pc) * RES_ + r) * 5;
        #pragma unroll
        for (int l = 0; l < 5; ++l) {
            float x = sp[l];
            float a;
            a = fmaxf(v0, x); x = fminf(v0, x); v0 = a;
            a = fmaxf(v1, x); x = fminf(v1, x); v1 = a;
            a = fmaxf(v2, x); x = fminf(v2, x); v2 = a;
            a = fmaxf(v3, x); x = fminf(v3, x); v3 = a;
            v4 = fmaxf(v4, x);
        }
    }
    float* o = out + (size_t)B_ * HW_ * HW_ + (size_t)b * (5 * RES_);
    o[r]            = v0;
    o[RES_ + r]     = v1;
    o[2 * RES_ + r] = v2;
    o[3 * RES_ + r] = v3;
    o[4 * RES_ + r] = v4;
}

extern "C" void kernel_launch(void* const* d_in, const int* in_sizes, int n_in,
                              void* d_out, int out_size, void* d_ws, size_t ws_size,
                              hipStream_t stream) {
    const float* pairs = (const float*)d_in[0];
    const float* sig   = (const float*)d_in[1];
    float* out = (float*)d_out;
    float* wsf = (float*)d_ws;

    // ws layout (floats): [0..63] minb, [64..127] maxd, [128..) land partials,
    // then image partials. Fall back KC/PC if ws is small.
    size_t availF = ws_size / 4;
    int PC = 8;
    while (PC > 1 &&
           (128 + (size_t)B_ * PC * RES_ * 5 + (size_t)B_ * HW_ * HW_) > availF)
        PC >>= 1;
    size_t landF = (size_t)B_ * PC * RES_ * 5;
    int KC = 16;
    while (KC > 1 && (128 + landF + (size_t)B_ * KC * HW_ * HW_) > availF)
        KC >>= 1;

    float* lp   = wsf + 128;
    float* part = wsf + 128 + landF;

    k_minmax<<<B_, 256, 0, stream>>>(pairs, wsf);
    k_img_partial<<<dim3(KC, B_), 64, 0, stream>>>(pairs, sig, part, KC);
    int chunk = N_ / PC;
    k_land_partial<<<dim3(PC, B_), 256, (size_t)chunk * 8, stream>>>(pairs, wsf, lp, PC);
    k_img_norm<<<B_, 256, 0, stream>>>(part, out, KC);
    k_land_merge<<<B_, 256, 0, stream>>>(lp, out, PC);
}

// Round 2
// 113.115 us; speedup vs baseline: 1.7657x; 1.7657x over previous
//
#include <hip/hip_runtime.h>
#include <math.h>

// TopologyHead: persistence image (B,64,64) + persistence landscapes (B,5,256)
// B=64, N=4096. Output = [image flat 262144][landscapes flat 81920], fp32.
//
//  k_minmax     : per-batch min birth / max death
//  k_img_stage  : bf16 MFMA K-split GEMM: image[b,h,w] = sum_n pers*gy*gx
//  k_img_reduce : sum KC=4 partials -> summed image + per-block max
//  k_img_scale  : normalize by per-batch max, write image
//  k_land_partial / k_land_merge : top-5 tent values per (b, r)

#define B_   64
#define N_   4096
#define HW_  64
#define RES_ 256
#define EPSF 1e-8f
#define KC_  4          // K-split for image GEMM (1024 points per block)
#define CPB  1024       // points per image block
#define KP   64         // points per staged LDS chunk

typedef short short8v  __attribute__((ext_vector_type(8)));
typedef float float4v  __attribute__((ext_vector_type(4)));

__device__ __forceinline__ unsigned short f2bf(float f) {
    unsigned int u = __float_as_uint(f);
    u += 0x7fffu + ((u >> 16) & 1u);          // round-nearest-even
    return (unsigned short)(u >> 16);
}

// ---------------- kernel 1: per-batch min birth / max death ----------------
__global__ __launch_bounds__(256) void k_minmax(const float* __restrict__ pairs,
                                                float* __restrict__ wsf) {
    int b = blockIdx.x, tid = threadIdx.x;
    const float2* pr = (const float2*)pairs + (size_t)b * N_;
    float mn = 1e30f, mx = -1e30f;
    #pragma unroll
    for (int i = 0; i < N_ / 256; ++i) {
        float2 v = pr[tid + i * 256];
        mn = fminf(mn, v.x);
        mx = fmaxf(mx, v.y);
    }
    #pragma unroll
    for (int off = 32; off > 0; off >>= 1) {
        mn = fminf(mn, __shfl_xor(mn, off, 64));
        mx = fmaxf(mx, __shfl_xor(mx, off, 64));
    }
    __shared__ float smn[4], smx[4];
    if ((tid & 63) == 0) { smn[tid >> 6] = mn; smx[tid >> 6] = mx; }
    __syncthreads();
    if (tid == 0) {
        mn = fminf(fminf(smn[0], smn[1]), fminf(smn[2], smn[3]));
        mx = fmaxf(fmaxf(smx[0], smx[1]), fmaxf(smx[2], smx[3]));
        wsf[b]      = mn;
        wsf[64 + b] = mx;
    }
}

// ------------- kernel 2: image partial via bf16 MFMA -------------
// Block = 256 thr (4 waves), one (batch, K-quarter). Wave w owns image rows
// [w*16, w*16+16) x all 64 cols as 4 C-tiles of 16x16x32 MFMA.
// LDS stride 72 bf16 (144 B) keeps b128 frag reads/stores at the 8-phase min.
__global__ __launch_bounds__(256) void k_img_stage(const float* __restrict__ pairs,
                                                   const float* __restrict__ sigp,
                                                   float* __restrict__ part) {
    __shared__ unsigned short gy_lds[64 * 72];   // [coord h][local k]  (pers-weighted)
    __shared__ unsigned short gx_lds[64 * 72];   // [coord w][local k]
    __shared__ float2 pts_lds[CPB];

    int kc = blockIdx.x, b = blockIdx.y;
    int tid = threadIdx.x;
    int l = tid & 63, w = tid >> 6;

    float sigma = sigp[0];
    float cc = 0.5f / (sigma * sigma);

    // load this block's 1024 points to LDS (coalesced float4)
    const float4* src = (const float4*)(pairs + 2 * ((size_t)b * N_ + kc * CPB));
    ((float4*)pts_lds)[tid]       = src[tid];
    ((float4*)pts_lds)[256 + tid] = src[256 + tid];

    int c  = tid & 63;          // coordinate this thread stages (grid_x == grid_y)
    int pg = tid >> 6;          // point sub-group
    float xc = (float)c * (1.0f / 63.0f);

    float4v acc[4];
    #pragma unroll
    for (int c4 = 0; c4 < 4; ++c4) acc[c4] = (float4v){0.f, 0.f, 0.f, 0.f};

    int rowA = (w * 16 + (l & 15)) * 72 + (l >> 4) * 8;   // A-frag base (bf16 idx)

    for (int ch = 0; ch < CPB / KP; ++ch) {
        __syncthreads();
        // ---- stage: 16 (coord,point) pairs per thread, 2 exps each ----
        int p0 = ch * KP + pg * 16;
        alignas(16) unsigned short gyb[16], gxb[16];
        #pragma unroll
        for (int j = 0; j < 16; ++j) {
            float2 q = pts_lds[p0 + j];           // LDS broadcast
            float pe = q.y - q.x;
            float dx = xc - q.x;
            float dy = xc - pe;
            gxb[j] = f2bf(__expf(-dx * dx * cc));
            gyb[j] = f2bf(pe * __expf(-dy * dy * cc));
        }
        *(uint4*)&gy_lds[c * 72 + pg * 16]     = *(uint4*)&gyb[0];
        *(uint4*)&gy_lds[c * 72 + pg * 16 + 8] = *(uint4*)&gyb[8];
        *(uint4*)&gx_lds[c * 72 + pg * 16]     = *(uint4*)&gxb[0];
        *(uint4*)&gx_lds[c * 72 + pg * 16 + 8] = *(uint4*)&gxb[8];
        __syncthreads();
        // ---- MFMA: 2 k-steps of 32 points, 4 col-tiles each ----
        #pragma unroll
        for (int ks = 0; ks < 2; ++ks) {
            short8v af = *(const short8v*)&gy_lds[rowA + ks * 32];
            #pragma unroll
            for (int c4 = 0; c4 < 4; ++c4) {
                short8v bf = *(const short8v*)
                    &gx_lds[(c4 * 16 + (l & 15)) * 72 + ks * 32 + (l >> 4) * 8];
                acc[c4] = __builtin_amdgcn_mfma_f32_16x16x32_bf16(af, bf, acc[c4], 0, 0, 0);
            }
        }
    }

    // epilogue: C/D layout col=lane&15, row=(lane>>4)*4+reg
    float* dst = part + (size_t)(b * KC_ + kc) * (HW_ * HW_);
    #pragma unroll
    for (int c4 = 0; c4 < 4; ++c4)
        #pragma unroll
        for (int reg = 0; reg < 4; ++reg) {
            int h = w * 16 + (l >> 4) * 4 + reg;
            int wv = c4 * 16 + (l & 15);
            dst[h * HW_ + wv] = acc[c4][reg];
        }
}

// ------------- kernel 3: sum KC partials, per-block max -------------
__global__ __launch_bounds__(256) void k_img_reduce(const float* __restrict__ part,
                                                    float* __restrict__ img,
                                                    float* __restrict__ bmax) {
    int blk = blockIdx.x, b = blockIdx.y, tid = threadIdx.x;
    int pix4 = blk * 256 + tid;                  // float4 index within image
    const float4* p0 = (const float4*)(part + (size_t)b * KC_ * (HW_ * HW_));
    float4 s = p0[pix4];
    #pragma unroll
    for (int kc = 1; kc < KC_; ++kc) {
        float4 v = p0[(size_t)kc * 1024 + pix4];
        s.x += v.x; s.y += v.y; s.z += v.z; s.w += v.w;
    }
    ((float4*)(img + (size_t)b * (HW_ * HW_)))[pix4] = s;
    float m = fmaxf(fmaxf(s.x, s.y), fmaxf(s.z, s.w));
    #pragma unroll
    for (int off = 32; off > 0; off >>= 1) m = fmaxf(m, __shfl_xor(m, off, 64));
    __shared__ float sm[4];
    if ((tid & 63) == 0) sm[tid >> 6] = m;
    __syncthreads();
    if (tid == 0)
        bmax[b * 4 + blk] = fmaxf(fmaxf(sm[0], sm[1]), fmaxf(sm[2], sm[3]));
}

// ------------- kernel 4: normalize -------------
__global__ __launch_bounds__(256) void k_img_scale(const float* __restrict__ img,
                                                   const float* __restrict__ bmax,
                                                   float* __restrict__ out) {
    int blk = blockIdx.x, b = blockIdx.y, tid = threadIdx.x;
    float m = fmaxf(fmaxf(bmax[b * 4], bmax[b * 4 + 1]),
                    fmaxf(bmax[b * 4 + 2], bmax[b * 4 + 3]));
    float inv = 1.0f / (m + EPSF);
    int pix4 = blk * 256 + tid;
    float4 v = ((const float4*)(img + (size_t)b * (HW_ * HW_)))[pix4];
    v.x *= inv; v.y *= inv; v.z *= inv; v.w *= inv;
    ((float4*)(out + (size_t)b * (HW_ * HW_)))[pix4] = v;
}

// ------------- kernel 5: landscape partial top-5 per (b, chunk, r) -------------
__global__ __launch_bounds__(256) void k_land_partial(const float* __restrict__ pairs,
                                                      const float* __restrict__ wsf,
                                                      float* __restrict__ lp, int PC) {
    extern __shared__ float4 pts[];               // chunk/2 float4 = chunk points
    int pc = blockIdx.x, b = blockIdx.y, tid = threadIdx.x;
    int chunk = N_ / PC;
    int n0 = pc * chunk;
    int np4 = chunk >> 1;
    const float4* src = (const float4*)(pairs + 2 * ((size_t)b * N_ + n0));
    for (int i = tid; i < np4; i += 256) pts[i] = src[i];
    __syncthreads();

    float minb = wsf[b], maxd = wsf[64 + b];
    float t_r = minb + (maxd - minb) * ((float)tid * (1.0f / 255.0f));

    float v0 = 0.f, v1 = 0.f, v2 = 0.f, v3 = 0.f, v4 = 0.f;  // tents >= 0
    #pragma unroll 4
    for (int p = 0; p < np4; ++p) {
        float4 q = pts[p];                        // broadcast read, 2 points
        {
            float x = fmaxf(fminf(t_r - q.x, q.y - t_r), 0.0f);
            float a;
            a = fmaxf(v0, x); x = fminf(v0, x); v0 = a;
            a = fmaxf(v1, x); x = fminf(v1, x); v1 = a;
            a = fmaxf(v2, x); x = fminf(v2, x); v2 = a;
            a = fmaxf(v3, x); x = fminf(v3, x); v3 = a;
            v4 = fmaxf(v4, x);
        }
        {
            float x = fmaxf(fminf(t_r - q.z, q.w - t_r), 0.0f);
            float a;
            a = fmaxf(v0, x); x = fminf(v0, x); v0 = a;
            a = fmaxf(v1, x); x = fminf(v1, x); v1 = a;
            a = fmaxf(v2, x); x = fminf(v2, x); v2 = a;
            a = fmaxf(v3, x); x = fminf(v3, x); v3 = a;
            v4 = fmaxf(v4, x);
        }
    }
    float* d = lp + ((size_t)(b * PC + pc) * RES_ + tid) * 5;
    d[0] = v0; d[1] = v1; d[2] = v2; d[3] = v3; d[4] = v4;
}

// ------------- kernel 6: merge PC partial top-5 lists -------------
__global__ __launch_bounds__(256) void k_land_merge(const float* __restrict__ lp,
                                                    float* __restrict__ out, int PC) {
    int b = blockIdx.x, r = threadIdx.x;
    const float* s0 = lp + ((size_t)b * PC * RES_ + r) * 5;
    float v0 = s0[0], v1 = s0[1], v2 = s0[2], v3 = s0[3], v4 = s0[4];
    for (int pc = 1; pc < PC; ++pc) {
        const float* sp = lp + ((size_t)(b * PC + pc) * RES_ + r) * 5;
        #pragma unroll
        for (int l = 0; l < 5; ++l) {
            float x = sp[l];
            float a;
            a = fmaxf(v0, x); x = fminf(v0, x); v0 = a;
            a = fmaxf(v1, x); x = fminf(v1, x); v1 = a;
            a = fmaxf(v2, x); x = fminf(v2, x); v2 = a;
            a = fmaxf(v3, x); x = fminf(v3, x); v3 = a;
            v4 = fmaxf(v4, x);
        }
    }
    float* o = out + (size_t)B_ * HW_ * HW_ + (size_t)b * (5 * RES_);
    o[r]            = v0;
    o[RES_ + r]     = v1;
    o[2 * RES_ + r] = v2;
    o[3 * RES_ + r] = v3;
    o[4 * RES_ + r] = v4;
}

extern "C" void kernel_launch(void* const* d_in, const int* in_sizes, int n_in,
                              void* d_out, int out_size, void* d_ws, size_t ws_size,
                              hipStream_t stream) {
    const float* pairs = (const float*)d_in[0];
    const float* sig   = (const float*)d_in[1];
    float* out = (float*)d_out;
    float* wsf = (float*)d_ws;

    // ws layout (floats): [0..63] minb | [64..127] maxd | [128..383] blockmax |
    // [384..) summed image (262144) | land partials | img partials (KC_*B*4096)
    size_t availF = ws_size / 4;
    int PC = 16;
    while (PC > 1 &&
           (384 + (size_t)B_ * HW_ * HW_ + (size_t)B_ * PC * RES_ * 5 +
            (size_t)B_ * KC_ * HW_ * HW_) > availF)
        PC >>= 1;
    size_t landF = (size_t)B_ * PC * RES_ * 5;

    float* bmax = wsf + 128;
    float* img  = wsf + 384;
    float* lp   = img + (size_t)B_ * HW_ * HW_;
    float* part = lp + landF;

    k_minmax<<<B_, 256, 0, stream>>>(pairs, wsf);
    k_img_stage<<<dim3(KC_, B_), 256, 0, stream>>>(pairs, sig, part);
    int chunk = N_ / PC;
    k_land_partial<<<dim3(PC, B_), 256, (size_t)chunk * 8, stream>>>(pairs, wsf, lp, PC);
    k_img_reduce<<<dim3(4, B_), 256, 0, stream>>>(part, img, bmax);
    k_img_scale<<<dim3(4, B_), 256, 0, stream>>>(img, bmax, out);
    k_land_merge<<<B_, 256, 0, stream>>>(lp, out, PC);
}

// Round 3
// 93.853 us; speedup vs baseline: 2.1281x; 1.2052x over previous
//
#include <hip/hip_runtime.h>
#include <math.h>

// TopologyHead: persistence image (B,64,64) + persistence landscapes (B,5,256)
// B=64, N=4096. Output = [image flat 262144][landscapes flat 81920], fp32.
//
// 3 dispatches:
//  k_minmax : per-batch min birth / max death -> wsf[0..127]
//  k_main   : blocks [0,256)   = image bf16-MFMA K-split GEMM (KC=4)
//             blocks [256,768) = landscape top-5 partials (1 wave per
//                                128-pt chunk, 4 r per lane, med3 insert,
//                                wave-uniform global point loads)
//  k_finish : per-batch: sum KC image partials + max + normalize;
//             merge 32 partial top-5 lists per r.

#define B_   64
#define N_   4096
#define HW_  64
#define RES_ 256
#define EPSF 1e-8f
#define KC_  4          // image K-split (1024 points per img block)
#define CPB  1024       // points per image block
#define KP   64         // points per staged LDS chunk (img)
#define PCW  32         // landscape point-chunks per batch (waves)
#define LCH  (N_ / PCW) // 128 points per landscape wave

typedef short short8v  __attribute__((ext_vector_type(8)));
typedef float float4v  __attribute__((ext_vector_type(4)));

__device__ __forceinline__ unsigned short f2bf(float f) {
    unsigned int u = __float_as_uint(f);
    u += 0x7fffu + ((u >> 16) & 1u);          // round-nearest-even
    return (unsigned short)(u >> 16);
}

// sorted-desc 5-list insert, 5 ops via med3; x<0 is a no-op (list >= 0)
#define INS5(v0, v1, v2, v3, v4, x)                       \
    {                                                     \
        float _p0 = v0, _p1 = v1, _p2 = v2, _p3 = v3;     \
        v0 = fmaxf(_p0, x);                               \
        v1 = __builtin_amdgcn_fmed3f(_p0, _p1, x);        \
        v2 = __builtin_amdgcn_fmed3f(_p1, _p2, x);        \
        v3 = __builtin_amdgcn_fmed3f(_p2, _p3, x);        \
        v4 = __builtin_amdgcn_fmed3f(_p3, v4, x);         \
    }

// ---------------- kernel 1: per-batch min birth / max death ----------------
__global__ __launch_bounds__(256) void k_minmax(const float* __restrict__ pairs,
                                                float* __restrict__ wsf) {
    int b = blockIdx.x, tid = threadIdx.x;
    const float2* pr = (const float2*)pairs + (size_t)b * N_;
    float mn = 1e30f, mx = -1e30f;
    #pragma unroll
    for (int i = 0; i < N_ / 256; ++i) {
        float2 v = pr[tid + i * 256];
        mn = fminf(mn, v.x);
        mx = fmaxf(mx, v.y);
    }
    #pragma unroll
    for (int off = 32; off > 0; off >>= 1) {
        mn = fminf(mn, __shfl_xor(mn, off, 64));
        mx = fmaxf(mx, __shfl_xor(mx, off, 64));
    }
    __shared__ float smn[4], smx[4];
    if ((tid & 63) == 0) { smn[tid >> 6] = mn; smx[tid >> 6] = mx; }
    __syncthreads();
    if (tid == 0) {
        mn = fminf(fminf(smn[0], smn[1]), fminf(smn[2], smn[3]));
        mx = fmaxf(fmaxf(smx[0], smx[1]), fmaxf(smx[2], smx[3]));
        wsf[b]      = mn;
        wsf[64 + b] = mx;
    }
}

// ---------------- kernel 2: fused image-MFMA + landscape partials ----------------
__global__ __launch_bounds__(256) void k_main(const float* __restrict__ pairs,
                                              const float* __restrict__ sigp,
                                              const float* __restrict__ wsf,
                                              float* __restrict__ part,
                                              float* __restrict__ lp) {
    __shared__ unsigned short gy_lds[64 * 72];
    __shared__ unsigned short gx_lds[64 * 72];
    __shared__ float2 pts_lds[CPB];

    int tid = threadIdx.x;
    int l = tid & 63, w = tid >> 6;

    if (blockIdx.x < 256) {
        // ================= image path: bf16 MFMA K-split GEMM =================
        int kc = blockIdx.x & 3, b = blockIdx.x >> 2;
        float sigma = sigp[0];
        float cc = 0.5f / (sigma * sigma);

        const float4* src = (const float4*)(pairs + 2 * ((size_t)b * N_ + kc * CPB));
        ((float4*)pts_lds)[tid]       = src[tid];
        ((float4*)pts_lds)[256 + tid] = src[256 + tid];

        int c  = tid & 63;          // coordinate this thread stages
        int pg = tid >> 6;          // point sub-group
        float xc = (float)c * (1.0f / 63.0f);

        float4v acc[4];
        #pragma unroll
        for (int c4 = 0; c4 < 4; ++c4) acc[c4] = (float4v){0.f, 0.f, 0.f, 0.f};

        int rowA = (w * 16 + (l & 15)) * 72 + (l >> 4) * 8;

        for (int ch = 0; ch < CPB / KP; ++ch) {
            __syncthreads();
            int p0 = ch * KP + pg * 16;
            alignas(16) unsigned short gyb[16], gxb[16];
            #pragma unroll
            for (int j = 0; j < 16; ++j) {
                float2 q = pts_lds[p0 + j];
                float pe = q.y - q.x;
                float dx = xc - q.x;
                float dy = xc - pe;
                gxb[j] = f2bf(__expf(-dx * dx * cc));
                gyb[j] = f2bf(pe * __expf(-dy * dy * cc));
            }
            *(uint4*)&gy_lds[c * 72 + pg * 16]     = *(uint4*)&gyb[0];
            *(uint4*)&gy_lds[c * 72 + pg * 16 + 8] = *(uint4*)&gyb[8];
            *(uint4*)&gx_lds[c * 72 + pg * 16]     = *(uint4*)&gxb[0];
            *(uint4*)&gx_lds[c * 72 + pg * 16 + 8] = *(uint4*)&gxb[8];
            __syncthreads();
            #pragma unroll
            for (int ks = 0; ks < 2; ++ks) {
                short8v af = *(const short8v*)&gy_lds[rowA + ks * 32];
                #pragma unroll
                for (int c4 = 0; c4 < 4; ++c4) {
                    short8v bf = *(const short8v*)
                        &gx_lds[(c4 * 16 + (l & 15)) * 72 + ks * 32 + (l >> 4) * 8];
                    acc[c4] = __builtin_amdgcn_mfma_f32_16x16x32_bf16(af, bf, acc[c4], 0, 0, 0);
                }
            }
        }

        float* dst = part + (size_t)(b * KC_ + kc) * (HW_ * HW_);
        #pragma unroll
        for (int c4 = 0; c4 < 4; ++c4)
            #pragma unroll
            for (int reg = 0; reg < 4; ++reg) {
                int h = w * 16 + (l >> 4) * 4 + reg;
                int wv = c4 * 16 + (l & 15);
                dst[h * HW_ + wv] = acc[c4][reg];
            }
    } else {
        // ================= landscape path: top-5 partials =================
        // one wave per 128-point chunk; lane owns r = l, l+64, l+128, l+192
        int idx = blockIdx.x - 256;            // 0..511
        int b = idx >> 3, pcb = idx & 7;
        int pc = pcb * 4 + w;                  // 0..31
        float minb = wsf[b], maxd = wsf[64 + b];
        float sc = (maxd - minb) * (1.0f / 255.0f);
        float t0 = minb + sc * (float)l;
        float t1 = t0 + sc * 64.0f;
        float t2 = t0 + sc * 128.0f;
        float t3 = t0 + sc * 192.0f;

        float a0 = 0.f, a1 = 0.f, a2 = 0.f, a3 = 0.f, a4 = 0.f;
        float b0 = 0.f, b1 = 0.f, b2 = 0.f, b3 = 0.f, b4 = 0.f;
        float c0 = 0.f, c1 = 0.f, c2 = 0.f, c3 = 0.f, c4 = 0.f;
        float d0 = 0.f, d1 = 0.f, d2 = 0.f, d3 = 0.f, d4 = 0.f;

        const float4* pw = (const float4*)(pairs + 2 * ((size_t)b * N_ + pc * LCH));
        #pragma unroll 4
        for (int p = 0; p < LCH / 2; ++p) {
            float4 q = pw[p];                  // wave-uniform, 2 points
            {
                float bb = q.x, dd = q.y;
                float x;
                x = fminf(t0 - bb, dd - t0); INS5(a0, a1, a2, a3, a4, x);
                x = fminf(t1 - bb, dd - t1); INS5(b0, b1, b2, b3, b4, x);
                x = fminf(t2 - bb, dd - t2); INS5(c0, c1, c2, c3, c4, x);
                x = fminf(t3 - bb, dd - t3); INS5(d0, d1, d2, d3, d4, x);
            }
            {
                float bb = q.z, dd = q.w;
                float x;
                x = fminf(t0 - bb, dd - t0); INS5(a0, a1, a2, a3, a4, x);
                x = fminf(t1 - bb, dd - t1); INS5(b0, b1, b2, b3, b4, x);
                x = fminf(t2 - bb, dd - t2); INS5(c0, c1, c2, c3, c4, x);
                x = fminf(t3 - bb, dd - t3); INS5(d0, d1, d2, d3, d4, x);
            }
        }

        // plane layout: lp[((b*PCW+pc)*5 + lvl)*RES + r] -- coalesced merge reads
        float* dst = lp + (size_t)(b * PCW + pc) * 5 * RES_;
        dst[0*RES_ + l]       = a0; dst[1*RES_ + l]       = a1;
        dst[2*RES_ + l]       = a2; dst[3*RES_ + l]       = a3;
        dst[4*RES_ + l]       = a4;
        dst[0*RES_ + l + 64]  = b0; dst[1*RES_ + l + 64]  = b1;
        dst[2*RES_ + l + 64]  = b2; dst[3*RES_ + l + 64]  = b3;
        dst[4*RES_ + l + 64]  = b4;
        dst[0*RES_ + l + 128] = c0; dst[1*RES_ + l + 128] = c1;
        dst[2*RES_ + l + 128] = c2; dst[3*RES_ + l + 128] = c3;
        dst[4*RES_ + l + 128] = c4;
        dst[0*RES_ + l + 192] = d0; dst[1*RES_ + l + 192] = d1;
        dst[2*RES_ + l + 192] = d2; dst[3*RES_ + l + 192] = d3;
        dst[4*RES_ + l + 192] = d4;
    }
}

// ---------------- kernel 3: image finish + landscape merge ----------------
__global__ __launch_bounds__(256) void k_finish(const float* __restrict__ part,
                                                const float* __restrict__ lp,
                                                float* __restrict__ out) {
    int b = blockIdx.x, tid = threadIdx.x;

    // ---- image: sum KC partials, block max, normalize ----
    const float4* p0 = (const float4*)(part + (size_t)b * KC_ * (HW_ * HW_));
    float4 s[4];
    float m = 0.0f;                                  // image values >= 0
    #pragma unroll
    for (int i = 0; i < 4; ++i) {
        int pix4 = tid + i * 256;
        float4 v = p0[pix4];
        #pragma unroll
        for (int kc = 1; kc < KC_; ++kc) {
            float4 u = p0[(size_t)kc * 1024 + pix4];
            v.x += u.x; v.y += u.y; v.z += u.z; v.w += u.w;
        }
        s[i] = v;
        m = fmaxf(m, fmaxf(fmaxf(v.x, v.y), fmaxf(v.z, v.w)));
    }
    #pragma unroll
    for (int off = 32; off > 0; off >>= 1) m = fmaxf(m, __shfl_xor(m, off, 64));
    __shared__ float sm[4];
    if ((tid & 63) == 0) sm[tid >> 6] = m;
    __syncthreads();
    m = fmaxf(fmaxf(sm[0], sm[1]), fmaxf(sm[2], sm[3]));
    float inv = 1.0f / (m + EPSF);
    float4* od = (float4*)(out + (size_t)b * (HW_ * HW_));
    #pragma unroll
    for (int i = 0; i < 4; ++i) {
        float4 v = s[i];
        v.x *= inv; v.y *= inv; v.z *= inv; v.w *= inv;
        od[tid + i * 256] = v;
    }

    // ---- landscapes: merge PCW partial top-5 lists for r = tid ----
    float v0 = 0.f, v1 = 0.f, v2 = 0.f, v3 = 0.f, v4 = 0.f;
    const float* lpb = lp + (size_t)b * PCW * 5 * RES_;
    for (int pc = 0; pc < PCW; ++pc) {
        #pragma unroll
        for (int lvl = 0; lvl < 5; ++lvl) {
            float x = lpb[(pc * 5 + lvl) * RES_ + tid];
            INS5(v0, v1, v2, v3, v4, x);
        }
    }
    float* o = out + (size_t)B_ * HW_ * HW_ + (size_t)b * (5 * RES_);
    o[tid]            = v0;
    o[RES_ + tid]     = v1;
    o[2 * RES_ + tid] = v2;
    o[3 * RES_ + tid] = v3;
    o[4 * RES_ + tid] = v4;
}

extern "C" void kernel_launch(void* const* d_in, const int* in_sizes, int n_in,
                              void* d_out, int out_size, void* d_ws, size_t ws_size,
                              hipStream_t stream) {
    const float* pairs = (const float*)d_in[0];
    const float* sig   = (const float*)d_in[1];
    float* out = (float*)d_out;
    float* wsf = (float*)d_ws;

    // ws layout (floats): [0..127] min/max | part (B*KC*4096 = 1M) | lp (B*32*5*256 = 2.62M)
    float* part = wsf + 128;
    float* lp   = part + (size_t)B_ * KC_ * HW_ * HW_;

    k_minmax<<<B_, 256, 0, stream>>>(pairs, wsf);
    k_main<<<768, 256, 0, stream>>>(pairs, sig, wsf, part, lp);
    k_finish<<<B_, 256, 0, stream>>>(part, lp, out);
}